// Round 16
// baseline (2830.005 us; speedup 1.0000x reference)
//
#include <hip/hip_runtime.h>
#include <hip/hip_bf16.h>

// Problem dims
#define BB 256
#define KK 512
#define UU 16
#define PP 64
#define HH 256
#define LL 64
#define THD 128   // 2*P
#define MB 16     // batch rows per group
#define NS 8      // unit-slices per group (32 GRU units each)
#define NG 16     // m-groups
#define NBLK (NG*NS)   // 128 blocks
#define NT 256

// LDS fragment regions (1 frag = 1KB = 512 f16; layout identical to R8/R10/R11)
#define WHH_F 0     // 6 nt * 8 kk = 48
#define WIH_F 48    // 6 nt * 2 kk = 12
#define WHD_F 60    // 8 nt * 8 kk = 64
#define WLF_F 124   // 4 nt * 3 kk = 12
#define NFRG 136

#define FP2 104     // f_M pitch (f16)
#define XP2 72      // x_M pitch (f16)

// h-exchange geometry (f16 elements)
#define HX_BUF 65536        // per-buffer: NG*MB*HH
#define HX_GRP 4096         // per-group: MB*HH

typedef _Float16 f16;
typedef _Float16 f16x8 __attribute__((ext_vector_type(8)));
typedef float f32x4 __attribute__((ext_vector_type(4)));
typedef unsigned u32x4 __attribute__((ext_vector_type(4)));

__device__ __forceinline__ float sigm(float x) { return 1.f / (1.f + __expf(-x)); }
__device__ __forceinline__ f32x4 MFMA(f16x8 a, f16x8 b, f32x4 c) {
  return __builtin_amdgcn_mfma_f32_16x16x32_f16(a, b, c, 0, 0, 0);
}

// R11-VERIFIED device-coherent (MALL) access — do not alter flags.
#define GLD16_S(dst, p) \
  asm volatile("global_load_dwordx4 %0, %1, off sc0 sc1" : "=&v"(dst) : "v"(p))
#define GSTH_S(p, v) \
  asm volatile("global_store_short %0, %1, off sc0 sc1" :: "v"(p), "v"(v) : "memory")
#define VM0() do { asm volatile("s_waitcnt vmcnt(0)" ::: "memory"); \
                   __builtin_amdgcn_sched_barrier(0); } while (0)

struct SM {
  alignas(16) f16 frg[NFRG * 512];       // 139264 B
  alignas(16) f16 x_M[MB * XP2];
  alignas(16) f16 f_M[MB * FP2];
  alignas(16) float ubuf[2][MB][UU];
  alignas(16) float jmp[UU * PP];
  float dts[2][MB];
  float bihs[96], bhhs[96];
  float bhead[THD];
  float blift[LL];
};

// stage one weight element into B-frag LDS layout (same k/n convention as R8)
__device__ __forceinline__ void put_frag(f16* frg, int base_f, int ntK, int nt,
                                         int n16, int k, float v) {
  int kk = k >> 5, lgp = (k >> 3) & 3, j = k & 7;
  int lane = lgp * 16 + n16;
  frg[(base_f + nt * ntK + kk) * 512 + lane * 8 + j] = (f16)v;
}

#define FRG(FID) (*(const f16x8*)&sm.frg[(FID) * 512 + lane * 8])

__global__ __launch_bounds__(NT) void odernn_coop(
    const float* __restrict__ y0, const float* __restrict__ u_seq,
    const float* __restrict__ dt_seq, const float* __restrict__ W_lift,
    const float* __restrict__ b_lift, const float* __restrict__ W_ih,
    const float* __restrict__ b_ih, const float* __restrict__ W_hh,
    const float* __restrict__ b_hh, const float* __restrict__ W_head,
    const float* __restrict__ b_head, const float* __restrict__ jump,
    f16* __restrict__ hx,
    float* __restrict__ out_y, float* __restrict__ out_th) {
  __shared__ SM sm;
  const int t = threadIdx.x;
  const int lane = t & 63, wv = t >> 6, lm = lane & 15, lg = lane >> 4;
  const int bid = blockIdx.x, g = bid >> 3, ns = bid & 7;
  const int g16 = g * MB;
  const int ub = 32 * ns;

  // ---- stage weight slices into LDS B-frag layout (verified R10/R11) ----
  for (int e = t; e < 96 * 256; e += NT) {
    int l = e >> 8, k = e & 255;
    int gate = l >> 5, ul = l & 31;
    put_frag(sm.frg, WHH_F, 8, l >> 4, l & 15, k, W_hh[(gate * 256 + ub + ul) * 256 + k]);
  }
  for (int e = t; e < 96 * 64; e += NT) {
    int l = e >> 6, k = e & 63;
    int gate = l >> 5, ul = l & 31;
    put_frag(sm.frg, WIH_F, 2, l >> 4, l & 15, k, W_ih[(gate * 256 + ub + ul) * 64 + k]);
  }
  for (int e = t; e < 128 * 256; e += NT) {
    int l = e >> 8, k = e & 255;
    put_frag(sm.frg, WHD_F, 8, l >> 4, l & 15, k, W_head[l * 256 + k]);
  }
  for (int e = t; e < 64 * 96; e += NT) {
    int l = e / 96, k = e - l * 96;
    float v = (k < UU + PP) ? W_lift[l * 80 + k] : 0.f;
    put_frag(sm.frg, WLF_F, 3, l >> 4, l & 15, k, v);
  }
  if (t < 96) { int gate = t >> 5, ul = t & 31;
    sm.bihs[t] = b_ih[gate * 256 + ub + ul];
    sm.bhhs[t] = b_hh[gate * 256 + ub + ul]; }
  if (t < THD) sm.bhead[t] = b_head[t];
  if (t < LL)  sm.blift[t] = b_lift[t];
  for (int e = t; e < UU * PP; e += NT) sm.jmp[e] = jump[e];
  for (int e = t; e < MB * FP2; e += NT) sm.f_M[e] = (f16)0.f;
  __syncthreads();
  if (t < 128) { int m = t >> 3, q = t & 7;
    float2 uv = *(const float2*)&u_seq[((size_t)(g16 + m) * KK) * UU + 2 * q];
    sm.ubuf[0][m][2 * q] = uv.x; sm.ubuf[0][m][2 * q + 1] = uv.y;
    sm.f_M[m * FP2 + 2 * q] = (f16)uv.x; sm.f_M[m * FP2 + 2 * q + 1] = (f16)uv.y; }
  if (t < MB) sm.dts[0][t] = dt_seq[(size_t)(g16 + t) * KK];
  // y registers in head/RK4 layout: (m = 4*lg + r, p = wv*16 + lm)
  const int myp = wv * 16 + lm;
  float yr[4];
#pragma unroll
  for (int r = 0; r < 4; ++r) {
    int m = 4 * lg + r;
    float yv = y0[(size_t)(g16 + m) * PP + myp];
    yr[r] = yv;
    sm.f_M[m * FP2 + UU + myp] = (f16)yv;
  }
  float ho[4] = {0.f, 0.f, 0.f, 0.f};
  f16x8 G0 = {}, G1 = {}, G2 = {}, G3 = {}, G4 = {}, G5 = {}, G6 = {}, G7 = {};
  __syncthreads();

#pragma unroll 1
  for (int j = 0; j < KK; ++j) {
    const int cb = j & 1, nb = cb ^ 1;
    const int negepoch = (j >> 1) & 1;               // sign epoch for this buffer use
    f32x4 aR = {0.f,0.f,0.f,0.f}, aZ = aR, aI = aR, aH = aR;
    const int ntr = wv, ntz = 2 + wv, ntn = 4 + wv;  // gate n-tiles (waves 0-1)

    // ---- ph1: waves 0-1: gates h-part (G regs, no x dep) ∥ waves 2-3: lift ----
    if (wv < 2) {
#define GR(kk, Gk) \
      aR = MFMA(Gk, FRG(WHH_F + ntr * 8 + kk), aR); \
      aZ = MFMA(Gk, FRG(WHH_F + ntz * 8 + kk), aZ); \
      aH = MFMA(Gk, FRG(WHH_F + ntn * 8 + kk), aH);
      GR(0, G0) GR(1, G1) GR(2, G2) GR(3, G3)
      GR(4, G4) GR(5, G5) GR(6, G6) GR(7, G7)
#undef GR
    } else {
      const int t0 = 2 * (wv - 2), t1 = t0 + 1;      // 2 lift n-tiles per wave
      const f16* fr = sm.f_M + lm * FP2 + lg * 8;
      f16x8 F0 = *(const f16x8*)(fr);
      f16x8 F1 = *(const f16x8*)(fr + 32);
      f16x8 F2 = *(const f16x8*)(fr + 64);
      f32x4 ax0 = {0.f, 0.f, 0.f, 0.f}, ax1 = ax0;
      ax0 = MFMA(F0, FRG(WLF_F + t0 * 3 + 0), ax0);
      ax1 = MFMA(F0, FRG(WLF_F + t1 * 3 + 0), ax1);
      ax0 = MFMA(F1, FRG(WLF_F + t0 * 3 + 1), ax0);
      ax1 = MFMA(F1, FRG(WLF_F + t1 * 3 + 1), ax1);
      ax0 = MFMA(F2, FRG(WLF_F + t0 * 3 + 2), ax0);
      ax1 = MFMA(F2, FRG(WLF_F + t1 * 3 + 2), ax1);
      const int c0 = t0 * 16 + lm, c1 = t1 * 16 + lm;
      const float bl0 = sm.blift[c0], bl1 = sm.blift[c1];
#pragma unroll
      for (int r = 0; r < 4; ++r) {
        float v0 = ax0[r] + bl0;
        sm.x_M[(4 * lg + r) * XP2 + c0] = (f16)(v0 * sigm(v0));   // silu
        float v1 = ax1[r] + bl1;
        sm.x_M[(4 * lg + r) * XP2 + c1] = (f16)(v1 * sigm(v1));
      }
    }
    __syncthreads();   // x_M ready

    // ---- ph2: waves 0-1: gates x-part + GRU + publish sign-epoch h' ∥ waves 2-3: prefetch ----
    if (wv < 2) {
      const f16* xr = sm.x_M + lm * XP2 + lg * 8;
      f16x8 X0 = *(const f16x8*)(xr);
      f16x8 X1 = *(const f16x8*)(xr + 32);
      aR = MFMA(X0, FRG(WIH_F + ntr * 2 + 0), aR);
      aZ = MFMA(X0, FRG(WIH_F + ntz * 2 + 0), aZ);
      aI = MFMA(X0, FRG(WIH_F + ntn * 2 + 0), aI);
      aR = MFMA(X1, FRG(WIH_F + ntr * 2 + 1), aR);
      aZ = MFMA(X1, FRG(WIH_F + ntz * 2 + 1), aZ);
      aI = MFMA(X1, FRG(WIH_F + ntn * 2 + 1), aI);
      const int ul = 16 * wv + lm;
      const float br = sm.bihs[ul] + sm.bhhs[ul];
      const float bz = sm.bihs[32 + ul] + sm.bhhs[32 + ul];
      const float bi = sm.bihs[64 + ul];
      const float bh2 = sm.bhhs[64 + ul];
      const float sgn = negepoch ? -1.f : 1.f;
      f16* hw = hx + cb * HX_BUF + g * HX_GRP + ub + ul;
#pragma unroll
      for (int r = 0; r < 4; ++r) {
        float rr = sigm(aR[r] + br);
        float zz = sigm(aZ[r] + bz);
        float nn = 2.f * sigm(2.f * (aI[r] + bi + rr * (aH[r] + bh2))) - 1.f;  // tanh
        float hv = (1.f - zz) * nn + zz * ho[r];
        ho[r] = hv;
        f16 h16 = (f16)(sgn * (hv + 2.f));           // self-validating encode
        unsigned hv32 = (unsigned)__builtin_bit_cast(unsigned short, h16);
        GSTH_S(hw + (4 * lg + r) * HH, hv32);
      }
      // NO flush, NO tag: freshness travels with each value's sign bit.
    } else if (j + 1 < KK) {
      const int idx = t - 128;
      const int m = idx >> 3, q = idx & 7;
      float2 uv = *(const float2*)&u_seq[((size_t)(g16 + m) * KK + (j + 1)) * UU + 2 * q];
      sm.ubuf[nb][m][2 * q] = uv.x; sm.ubuf[nb][m][2 * q + 1] = uv.y;
      sm.f_M[m * FP2 + 2 * q] = (f16)uv.x; sm.f_M[m * FP2 + 2 * q + 1] = (f16)uv.y;
      if (idx < MB) sm.dts[nb][idx] = dt_seq[(size_t)(g16 + idx) * KK + (j + 1)];
    }

    // ---- ph3: sleep -> per-wave poll on h data -> decode -> head -> theta+RK4 in reg ----
    {
      asm volatile("s_sleep 8");        // ~512cy: let writers' stores land first
      const unsigned want = negepoch ? 0x80008000u : 0u;
      const f16* hb2 = hx + cb * HX_BUF + g * HX_GRP + lm * HH + lg * 8;
      int guard = 4096; int ok;
      do {
        GLD16_S(G0, hb2);        GLD16_S(G1, hb2 + 32);
        GLD16_S(G2, hb2 + 64);   GLD16_S(G3, hb2 + 96);
        GLD16_S(G4, hb2 + 128);  GLD16_S(G5, hb2 + 160);
        GLD16_S(G6, hb2 + 192);  GLD16_S(G7, hb2 + 224);
        VM0();
        unsigned bad = 0u;
#define CK(Gk) { u32x4 u_ = __builtin_bit_cast(u32x4, Gk); \
        bad |= (u_.x ^ want) & 0x80008000u; bad |= (u_.y ^ want) & 0x80008000u; \
        bad |= (u_.z ^ want) & 0x80008000u; bad |= (u_.w ^ want) & 0x80008000u; }
        CK(G0) CK(G1) CK(G2) CK(G3) CK(G4) CK(G5) CK(G6) CK(G7)
#undef CK
        ok = __all(bad == 0u);
      } while (!ok && --guard);
      __builtin_amdgcn_sched_barrier(0);
      // decode: h = sgn*h' - 2  (negepoch: -2 - h' ; else: h' - 2)
      {
        const f16 m2 = (f16)(-2.f);
        const f16x8 M2 = {m2, m2, m2, m2, m2, m2, m2, m2};
        if (negepoch) {
          G0 = M2 - G0; G1 = M2 - G1; G2 = M2 - G2; G3 = M2 - G3;
          G4 = M2 - G4; G5 = M2 - G5; G6 = M2 - G6; G7 = M2 - G7;
        } else {
          G0 = G0 + M2; G1 = G1 + M2; G2 = G2 + M2; G3 = G3 + M2;
          G4 = G4 + M2; G5 = G5 + M2; G6 = G6 + M2; G7 = G7 + M2;
        }
      }
      f32x4 acc0 = {0.f,0.f,0.f,0.f}, acc1 = acc0;
#define HD(kk, Gk) \
      acc0 = MFMA(Gk, FRG(WHD_F + wv * 8 + kk), acc0); \
      acc1 = MFMA(Gk, FRG(WHD_F + (wv + 4) * 8 + kk), acc1);
      HD(0, G0) HD(1, G1) HD(2, G2) HD(3, G3)
      HD(4, G4) HD(5, G5) HD(6, G6) HD(7, G7)
#undef HD
      // theta in registers: thread owns (m=4lg+r, p=myp): a=th0[r], drive=th1[r]
      const float b0 = sm.bhead[myp];
      const float b1 = sm.bhead[64 + myp];
      float th0[4], th1[4];
#pragma unroll
      for (int r = 0; r < 4; ++r) {
        th0[r] = 0.001f + 1.999f * sigm(acc0[r] + b0);
        th1[r] = 0.001f + 1.999f * sigm(acc1[r] + b1);
      }
      // jump + RK4 + clamp, all in-register
      float jv[UU];
#pragma unroll
      for (int uu = 0; uu < UU; ++uu) jv[uu] = sm.jmp[uu * PP + myp];
#pragma unroll
      for (int r = 0; r < 4; ++r) {
        const int m = 4 * lg + r;
        const float hdt = sm.dts[cb][m];
        float yv = yr[r];
#pragma unroll
        for (int uu = 0; uu < UU; ++uu) yv = fmaf(sm.ubuf[cb][m][uu], jv[uu], yv);
        float a = th0[r], dr = th1[r];
        float k1 = dr - a * yv;
        float k2 = dr - a * fmaf(0.5f * hdt, k1, yv);
        float k3 = dr - a * fmaf(0.5f * hdt, k2, yv);
        float k4 = dr - a * fmaf(hdt, k3, yv);
        yv = yv + (hdt * (1.f / 6.f)) * (k1 + 2.f * k2 + 2.f * k3 + k4);
        yv = fmaxf(yv, 0.f);
        yr[r] = yv;
        sm.f_M[m * FP2 + UU + myp] = (f16)yv;        // feat y-part for step j+1
        if (ns == 0) {
          out_y[((size_t)(g16 + m) * KK + j) * PP + myp] = yv;
          out_th[((size_t)(g16 + m) * KK + j) * THD + myp] = a;
          out_th[((size_t)(g16 + m) * KK + j) * THD + 64 + myp] = dr;
        }
      }
    }
    __syncthreads();   // f_M y-part ready for next lift
  }
}

extern "C" void kernel_launch(void* const* d_in, const int* in_sizes, int n_in,
                              void* d_out, int out_size, void* d_ws, size_t ws_size,
                              hipStream_t stream) {
  (void)in_sizes; (void)n_in; (void)out_size; (void)ws_size;
  const float* y0     = (const float*)d_in[0];
  const float* u_seq  = (const float*)d_in[1];
  const float* dt_seq = (const float*)d_in[2];
  const float* W_lift = (const float*)d_in[3];
  const float* b_lift = (const float*)d_in[4];
  const float* W_ih   = (const float*)d_in[5];
  const float* b_ih   = (const float*)d_in[6];
  const float* W_hh   = (const float*)d_in[7];
  const float* b_hh   = (const float*)d_in[8];
  const float* W_head = (const float*)d_in[9];
  const float* b_head = (const float*)d_in[10];
  const float* jump   = (const float*)d_in[11];
  float* outy = (float*)d_out;
  float* outt = outy + (size_t)BB * KK * PP;
  f16* hx = (f16*)d_ws;

  // 0xAA bytes -> 0xAAAA f16 = negative sign = stale for j=0/1 (expect +).
  // Must run every launch (deterministic; resets the sign-epoch chain).
  hipMemsetAsync(d_ws, 0xAA, (size_t)2 * HX_BUF * sizeof(f16), stream);
  void* args[] = {
    (void*)&y0, (void*)&u_seq, (void*)&dt_seq, (void*)&W_lift, (void*)&b_lift,
    (void*)&W_ih, (void*)&b_ih, (void*)&W_hh, (void*)&b_hh, (void*)&W_head,
    (void*)&b_head, (void*)&jump, (void*)&hx, (void*)&outy, (void*)&outt
  };
  hipLaunchCooperativeKernel((const void*)odernn_coop, dim3(NBLK), dim3(NT),
                             args, 0, stream);
}

// Round 17
// 2231.890 us; speedup vs baseline: 1.2680x; 1.2680x over previous
//
#include <hip/hip_runtime.h>
#include <hip/hip_bf16.h>

// Problem dims
#define BB 256
#define KK 512
#define UU 16
#define PP 64
#define HH 256
#define LL 64
#define THD 128   // 2*P
#define MB 16     // batch rows per group
#define NS 8      // unit-slices per group (32 GRU units each)
#define NG 16     // m-groups
#define NBLK (NG*NS)   // 128 blocks
#define NT 256

// LDS fragment regions (1 frag = 1KB = 512 f16; layout identical to R8/R10/R11)
#define WHH_F 0     // 6 nt * 8 kk = 48
#define WIH_F 48    // 6 nt * 2 kk = 12
#define WHD_F 60    // 8 nt * 8 kk = 64
#define WLF_F 124   // 4 nt * 3 kk = 12
#define NFRG 136

#define FP2 104     // f_M pitch (f16)
#define XP2 72      // x_M pitch (f16)

// h-exchange geometry (f16 elements), SLICE-MAJOR: [buf][g][ns][row16][unit32]
#define HX_BUF 65536        // per-buffer: NG*MB*HH
#define HX_GRP 4096         // per-group: MB*HH

typedef _Float16 f16;
typedef _Float16 f16x4 __attribute__((ext_vector_type(4)));
typedef _Float16 f16x8 __attribute__((ext_vector_type(8)));
typedef float f32x4 __attribute__((ext_vector_type(4)));
typedef unsigned u32x2 __attribute__((ext_vector_type(2)));
typedef unsigned u32x4 __attribute__((ext_vector_type(4)));

__device__ __forceinline__ float sigm(float x) { return 1.f / (1.f + __expf(-x)); }
__device__ __forceinline__ f32x4 MFMA(f16x8 a, f16x8 b, f32x4 c) {
  return __builtin_amdgcn_mfma_f32_16x16x32_f16(a, b, c, 0, 0, 0);
}

// R11-VERIFIED device-coherent (MALL) access — do not alter flags.
#define GLD16_S(dst, p) \
  asm volatile("global_load_dwordx4 %0, %1, off sc0 sc1" : "=&v"(dst) : "v"(p))
#define GSTX2_S(p, v) \
  asm volatile("global_store_dwordx2 %0, %1, off sc0 sc1" :: "v"(p), "v"(v) : "memory")
#define VM0() do { asm volatile("s_waitcnt vmcnt(0)" ::: "memory"); \
                   __builtin_amdgcn_sched_barrier(0); } while (0)

struct SM {
  alignas(16) f16 frg[NFRG * 512];       // 139264 B
  alignas(16) f16 hstg[16 * 32];         // 1KB h'-slice staging (transpose)
  alignas(16) f16 x_M[MB * XP2];
  alignas(16) f16 f_M[MB * FP2];
  alignas(16) float ubuf[2][MB][UU];
  alignas(16) float jmp[UU * PP];
  float dts[2][MB];
  float bihs[96], bhhs[96];
  float bhead[THD];
  float blift[LL];
};

// stage one weight element into B-frag LDS layout (same k/n convention as R8)
__device__ __forceinline__ void put_frag(f16* frg, int base_f, int ntK, int nt,
                                         int n16, int k, float v) {
  int kk = k >> 5, lgp = (k >> 3) & 3, j = k & 7;
  int lane = lgp * 16 + n16;
  frg[(base_f + nt * ntK + kk) * 512 + lane * 8 + j] = (f16)v;
}

#define FRG(FID) (*(const f16x8*)&sm.frg[(FID) * 512 + lane * 8])

__global__ __launch_bounds__(NT) void odernn_coop(
    const float* __restrict__ y0, const float* __restrict__ u_seq,
    const float* __restrict__ dt_seq, const float* __restrict__ W_lift,
    const float* __restrict__ b_lift, const float* __restrict__ W_ih,
    const float* __restrict__ b_ih, const float* __restrict__ W_hh,
    const float* __restrict__ b_hh, const float* __restrict__ W_head,
    const float* __restrict__ b_head, const float* __restrict__ jump,
    f16* __restrict__ hx,
    float* __restrict__ out_y, float* __restrict__ out_th) {
  __shared__ SM sm;
  const int t = threadIdx.x;
  const int lane = t & 63, wv = t >> 6, lm = lane & 15, lg = lane >> 4;
  const int bid = blockIdx.x, g = bid >> 3, ns = bid & 7;
  const int g16 = g * MB;
  const int ub = 32 * ns;

  // ---- stage weight slices into LDS B-frag layout (verified R10/R11) ----
  for (int e = t; e < 96 * 256; e += NT) {
    int l = e >> 8, k = e & 255;
    int gate = l >> 5, ul = l & 31;
    put_frag(sm.frg, WHH_F, 8, l >> 4, l & 15, k, W_hh[(gate * 256 + ub + ul) * 256 + k]);
  }
  for (int e = t; e < 96 * 64; e += NT) {
    int l = e >> 6, k = e & 63;
    int gate = l >> 5, ul = l & 31;
    put_frag(sm.frg, WIH_F, 2, l >> 4, l & 15, k, W_ih[(gate * 256 + ub + ul) * 64 + k]);
  }
  for (int e = t; e < 128 * 256; e += NT) {
    int l = e >> 8, k = e & 255;
    put_frag(sm.frg, WHD_F, 8, l >> 4, l & 15, k, W_head[l * 256 + k]);
  }
  for (int e = t; e < 64 * 96; e += NT) {
    int l = e / 96, k = e - l * 96;
    float v = (k < UU + PP) ? W_lift[l * 80 + k] : 0.f;
    put_frag(sm.frg, WLF_F, 3, l >> 4, l & 15, k, v);
  }
  if (t < 96) { int gate = t >> 5, ul = t & 31;
    sm.bihs[t] = b_ih[gate * 256 + ub + ul];
    sm.bhhs[t] = b_hh[gate * 256 + ub + ul]; }
  if (t < THD) sm.bhead[t] = b_head[t];
  if (t < LL)  sm.blift[t] = b_lift[t];
  for (int e = t; e < UU * PP; e += NT) sm.jmp[e] = jump[e];
  for (int e = t; e < MB * FP2; e += NT) sm.f_M[e] = (f16)0.f;
  __syncthreads();
  if (t < 128) { int m = t >> 3, q = t & 7;
    float2 uv = *(const float2*)&u_seq[((size_t)(g16 + m) * KK) * UU + 2 * q];
    sm.ubuf[0][m][2 * q] = uv.x; sm.ubuf[0][m][2 * q + 1] = uv.y;
    sm.f_M[m * FP2 + 2 * q] = (f16)uv.x; sm.f_M[m * FP2 + 2 * q + 1] = (f16)uv.y; }
  if (t < MB) sm.dts[0][t] = dt_seq[(size_t)(g16 + t) * KK];
  // y registers in head/RK4 layout: (m = 4*lg + r, p = wv*16 + lm)
  const int myp = wv * 16 + lm;
  float yr[4];
#pragma unroll
  for (int r = 0; r < 4; ++r) {
    int m = 4 * lg + r;
    float yv = y0[(size_t)(g16 + m) * PP + myp];
    yr[r] = yv;
    sm.f_M[m * FP2 + UU + myp] = (f16)yv;
  }
  float ho[4] = {0.f, 0.f, 0.f, 0.f};
  f16x8 G0 = {}, G1 = {}, G2 = {}, G3 = {}, G4 = {}, G5 = {}, G6 = {}, G7 = {};
  __syncthreads();

#pragma unroll 1
  for (int j = 0; j < KK; ++j) {
    const int cb = j & 1, nb = cb ^ 1;
    const int negepoch = (j >> 1) & 1;               // sign epoch for this buffer use
    f32x4 aR = {0.f,0.f,0.f,0.f}, aZ = aR, aI = aR, aH = aR;
    const int ntr = wv, ntz = 2 + wv, ntn = 4 + wv;  // gate n-tiles (waves 0-1)

    // ---- ph1: waves 0-1: gates h-part (G regs, no x dep) ∥ waves 2-3: lift ----
    if (wv < 2) {
#define GR(kk, Gk) \
      aR = MFMA(Gk, FRG(WHH_F + ntr * 8 + kk), aR); \
      aZ = MFMA(Gk, FRG(WHH_F + ntz * 8 + kk), aZ); \
      aH = MFMA(Gk, FRG(WHH_F + ntn * 8 + kk), aH);
      GR(0, G0) GR(1, G1) GR(2, G2) GR(3, G3)
      GR(4, G4) GR(5, G5) GR(6, G6) GR(7, G7)
#undef GR
    } else {
      const int t0 = 2 * (wv - 2), t1 = t0 + 1;      // 2 lift n-tiles per wave
      const f16* fr = sm.f_M + lm * FP2 + lg * 8;
      f16x8 F0 = *(const f16x8*)(fr);
      f16x8 F1 = *(const f16x8*)(fr + 32);
      f16x8 F2 = *(const f16x8*)(fr + 64);
      f32x4 ax0 = {0.f, 0.f, 0.f, 0.f}, ax1 = ax0;
      ax0 = MFMA(F0, FRG(WLF_F + t0 * 3 + 0), ax0);
      ax1 = MFMA(F0, FRG(WLF_F + t1 * 3 + 0), ax1);
      ax0 = MFMA(F1, FRG(WLF_F + t0 * 3 + 1), ax0);
      ax1 = MFMA(F1, FRG(WLF_F + t1 * 3 + 1), ax1);
      ax0 = MFMA(F2, FRG(WLF_F + t0 * 3 + 2), ax0);
      ax1 = MFMA(F2, FRG(WLF_F + t1 * 3 + 2), ax1);
      const int c0 = t0 * 16 + lm, c1 = t1 * 16 + lm;
      const float bl0 = sm.blift[c0], bl1 = sm.blift[c1];
#pragma unroll
      for (int r = 0; r < 4; ++r) {
        float v0 = ax0[r] + bl0;
        sm.x_M[(4 * lg + r) * XP2 + c0] = (f16)(v0 * sigm(v0));   // silu
        float v1 = ax1[r] + bl1;
        sm.x_M[(4 * lg + r) * XP2 + c1] = (f16)(v1 * sigm(v1));
      }
    }
    __syncthreads();   // x_M ready

    // ---- ph2: waves 0-1: gates x-part + GRU -> h' into LDS staging ----
    //          waves 2-3: ISSUE u/dt loads to regs (write-late after barrier, T14)
    float2 pf_uv; float pf_dt = 0.f;
    if (wv < 2) {
      const f16* xr = sm.x_M + lm * XP2 + lg * 8;
      f16x8 X0 = *(const f16x8*)(xr);
      f16x8 X1 = *(const f16x8*)(xr + 32);
      aR = MFMA(X0, FRG(WIH_F + ntr * 2 + 0), aR);
      aZ = MFMA(X0, FRG(WIH_F + ntz * 2 + 0), aZ);
      aI = MFMA(X0, FRG(WIH_F + ntn * 2 + 0), aI);
      aR = MFMA(X1, FRG(WIH_F + ntr * 2 + 1), aR);
      aZ = MFMA(X1, FRG(WIH_F + ntz * 2 + 1), aZ);
      aI = MFMA(X1, FRG(WIH_F + ntn * 2 + 1), aI);
      const int ul = 16 * wv + lm;
      const float br = sm.bihs[ul] + sm.bhhs[ul];
      const float bz = sm.bihs[32 + ul] + sm.bhhs[32 + ul];
      const float bi = sm.bihs[64 + ul];
      const float bh2 = sm.bhhs[64 + ul];
      const float sgn = negepoch ? -1.f : 1.f;
#pragma unroll
      for (int r = 0; r < 4; ++r) {
        float rr = sigm(aR[r] + br);
        float zz = sigm(aZ[r] + bz);
        float nn = 2.f * sigm(2.f * (aI[r] + bi + rr * (aH[r] + bh2))) - 1.f;  // tanh
        float hv = (1.f - zz) * nn + zz * ho[r];
        ho[r] = hv;
        sm.hstg[(4 * lg + r) * 32 + ul] = (f16)(sgn * (hv + 2.f));  // encode
      }
    } else if (j + 1 < KK) {
      const int idx = t - 128;
      const int m = idx >> 3, q = idx & 7;
      pf_uv = *(const float2*)&u_seq[((size_t)(g16 + m) * KK + (j + 1)) * UU + 2 * q];
      if (idx < MB) pf_dt = dt_seq[(size_t)(g16 + idx) * KK + (j + 1)];
    }
    __syncthreads();   // hstg complete block-wide

    // ---- ph2b: waves 0-1: coalesced h publish (1KB contiguous, 1 dwordx2/lane)
    //           waves 2-3: commit prefetched u/dt to LDS ----
    if (wv < 2) {
      const int row = t >> 3, part = t & 7;          // t in [0,128)
      f16x4 hv4 = *(const f16x4*)&sm.hstg[row * 32 + part * 4];
      u32x2 w = __builtin_bit_cast(u32x2, hv4);
      f16* dst = hx + cb * HX_BUF + g * HX_GRP + ns * 512 + row * 32 + part * 4;
      GSTX2_S(dst, w);
      // fire-and-forget: freshness travels with each value's sign bit.
    } else if (j + 1 < KK) {
      const int idx = t - 128;
      const int m = idx >> 3, q = idx & 7;
      sm.ubuf[nb][m][2 * q] = pf_uv.x; sm.ubuf[nb][m][2 * q + 1] = pf_uv.y;
      sm.f_M[m * FP2 + 2 * q] = (f16)pf_uv.x; sm.f_M[m * FP2 + 2 * q + 1] = (f16)pf_uv.y;
      if (idx < MB) sm.dts[nb][idx] = pf_dt;
    }

    // ---- ph3: per-wave poll on h data (slice-major) -> decode -> head -> theta+RK4 ----
    {
      const unsigned want = negepoch ? 0x80008000u : 0u;
      const f16* hb2 = hx + cb * HX_BUF + g * HX_GRP + lm * 32 + lg * 8;
      int guard = 4096; int ok;
      do {
        GLD16_S(G0, hb2);          GLD16_S(G1, hb2 + 512);
        GLD16_S(G2, hb2 + 1024);   GLD16_S(G3, hb2 + 1536);
        GLD16_S(G4, hb2 + 2048);   GLD16_S(G5, hb2 + 2560);
        GLD16_S(G6, hb2 + 3072);   GLD16_S(G7, hb2 + 3584);
        VM0();
        unsigned bad = 0u;
#define CK(Gk) { u32x4 u_ = __builtin_bit_cast(u32x4, Gk); \
        bad |= (u_.x ^ want) & 0x80008000u; bad |= (u_.y ^ want) & 0x80008000u; \
        bad |= (u_.z ^ want) & 0x80008000u; bad |= (u_.w ^ want) & 0x80008000u; }
        CK(G0) CK(G1) CK(G2) CK(G3) CK(G4) CK(G5) CK(G6) CK(G7)
#undef CK
        ok = __all(bad == 0u);
      } while (!ok && --guard);
      __builtin_amdgcn_sched_barrier(0);
      // decode: h = sgn*h' - 2  (negepoch: -2 - h' ; else: h' - 2)
      {
        const f16 m2 = (f16)(-2.f);
        const f16x8 M2 = {m2, m2, m2, m2, m2, m2, m2, m2};
        if (negepoch) {
          G0 = M2 - G0; G1 = M2 - G1; G2 = M2 - G2; G3 = M2 - G3;
          G4 = M2 - G4; G5 = M2 - G5; G6 = M2 - G6; G7 = M2 - G7;
        } else {
          G0 = G0 + M2; G1 = G1 + M2; G2 = G2 + M2; G3 = G3 + M2;
          G4 = G4 + M2; G5 = G5 + M2; G6 = G6 + M2; G7 = G7 + M2;
        }
      }
      f32x4 acc0 = {0.f,0.f,0.f,0.f}, acc1 = acc0;
#define HD(kk, Gk) \
      acc0 = MFMA(Gk, FRG(WHD_F + wv * 8 + kk), acc0); \
      acc1 = MFMA(Gk, FRG(WHD_F + (wv + 4) * 8 + kk), acc1);
      HD(0, G0) HD(1, G1) HD(2, G2) HD(3, G3)
      HD(4, G4) HD(5, G5) HD(6, G6) HD(7, G7)
#undef HD
      // theta in registers: thread owns (m=4lg+r, p=myp): a=th0[r], drive=th1[r]
      const float b0 = sm.bhead[myp];
      const float b1 = sm.bhead[64 + myp];
      float th0[4], th1[4];
#pragma unroll
      for (int r = 0; r < 4; ++r) {
        th0[r] = 0.001f + 1.999f * sigm(acc0[r] + b0);
        th1[r] = 0.001f + 1.999f * sigm(acc1[r] + b1);
      }
      // jump + RK4 + clamp, all in-register
      float jv[UU];
#pragma unroll
      for (int uu = 0; uu < UU; ++uu) jv[uu] = sm.jmp[uu * PP + myp];
#pragma unroll
      for (int r = 0; r < 4; ++r) {
        const int m = 4 * lg + r;
        const float hdt = sm.dts[cb][m];
        float yv = yr[r];
#pragma unroll
        for (int uu = 0; uu < UU; ++uu) yv = fmaf(sm.ubuf[cb][m][uu], jv[uu], yv);
        float a = th0[r], dr = th1[r];
        float k1 = dr - a * yv;
        float k2 = dr - a * fmaf(0.5f * hdt, k1, yv);
        float k3 = dr - a * fmaf(0.5f * hdt, k2, yv);
        float k4 = dr - a * fmaf(hdt, k3, yv);
        yv = yv + (hdt * (1.f / 6.f)) * (k1 + 2.f * k2 + 2.f * k3 + k4);
        yv = fmaxf(yv, 0.f);
        yr[r] = yv;
        sm.f_M[m * FP2 + UU + myp] = (f16)yv;        // feat y-part for step j+1
        if (ns == 0) {
          out_y[((size_t)(g16 + m) * KK + j) * PP + myp] = yv;
          out_th[((size_t)(g16 + m) * KK + j) * THD + myp] = a;
          out_th[((size_t)(g16 + m) * KK + j) * THD + 64 + myp] = dr;
        }
      }
    }
    __syncthreads();   // f_M y-part ready for next lift
  }
}

extern "C" void kernel_launch(void* const* d_in, const int* in_sizes, int n_in,
                              void* d_out, int out_size, void* d_ws, size_t ws_size,
                              hipStream_t stream) {
  (void)in_sizes; (void)n_in; (void)out_size; (void)ws_size;
  const float* y0     = (const float*)d_in[0];
  const float* u_seq  = (const float*)d_in[1];
  const float* dt_seq = (const float*)d_in[2];
  const float* W_lift = (const float*)d_in[3];
  const float* b_lift = (const float*)d_in[4];
  const float* W_ih   = (const float*)d_in[5];
  const float* b_ih   = (const float*)d_in[6];
  const float* W_hh   = (const float*)d_in[7];
  const float* b_hh   = (const float*)d_in[8];
  const float* W_head = (const float*)d_in[9];
  const float* b_head = (const float*)d_in[10];
  const float* jump   = (const float*)d_in[11];
  float* outy = (float*)d_out;
  float* outt = outy + (size_t)BB * KK * PP;
  f16* hx = (f16*)d_ws;

  // 0xAA bytes -> 0xAAAA f16 = negative sign = stale for j=0/1 (expect +).
  // Must run every launch (deterministic; resets the sign-epoch chain).
  hipMemsetAsync(d_ws, 0xAA, (size_t)2 * HX_BUF * sizeof(f16), stream);
  void* args[] = {
    (void*)&y0, (void*)&u_seq, (void*)&dt_seq, (void*)&W_lift, (void*)&b_lift,
    (void*)&W_ih, (void*)&b_ih, (void*)&W_hh, (void*)&b_hh, (void*)&W_head,
    (void*)&b_head, (void*)&jump, (void*)&hx, (void*)&outy, (void*)&outt
  };
  hipLaunchCooperativeKernel((const void*)odernn_coop, dim3(NBLK), dim3(NT),
                             args, 0, stream);
}